// Round 3
// baseline (531.179 us; speedup 1.0000x reference)
//
#include <hip/hip_runtime.h>
#include <hip/hip_bf16.h>
#include <stdint.h>
#include <stddef.h>

// ---------- types ----------
typedef __attribute__((ext_vector_type(8)))  __bf16 bf16x8;   // MFMA A/B frag (4 VGPRs)
typedef __attribute__((ext_vector_type(16))) float  f32x16;   // 32x32 MFMA C/D frag
typedef __attribute__((ext_vector_type(8)))  unsigned short ushort8;

typedef const void __attribute__((address_space(1)))* as1_cvp;
typedef void       __attribute__((address_space(3)))* as3_vp;

__device__ __forceinline__ void gload_lds16(const void* g, void* l) {
    // width=16 -> global_load_lds_dwordx4. LDS dest = wave-uniform base + lane*16.
    __builtin_amdgcn_global_load_lds((as1_cvp)g, (as3_vp)l, 16, 0, 0);
}

__device__ __forceinline__ unsigned short f2bf(float f) {
    union { float f; unsigned u; } v; v.f = f;
    unsigned r = v.u + 0x7fffu + ((v.u >> 16) & 1u);   // RNE
    return (unsigned short)(r >> 16);
}

// ---------- kernel 1 (fused prep): blocks [0,nW) -> Wb row; blocks [nW,..) -> x cast ----------
// UNCHANGED (isolating the GEMM change).
__global__ __launch_bounds__(256) void prep_kernel(
    const float* __restrict__ x,
    const float* __restrict__ W,
    const float* __restrict__ A1, const float* __restrict__ B1,
    const float* __restrict__ A2, const float* __restrict__ B2,
    unsigned short* __restrict__ Xb, unsigned short* __restrict__ Wb,
    int d, int nW, int n8)
{
    int blk = blockIdx.x;
    if (blk < nW) {
        int o  = blk;
        int k0 = threadIdx.x * 8;
        const float4* wrow = (const float4*)(W + (size_t)o * d + k0);
        float4 w0 = wrow[0], w1 = wrow[1];
        float acc[8] = {w0.x, w0.y, w0.z, w0.w, w1.x, w1.y, w1.z, w1.w};
        if (o >= d) {                               // block-uniform branch
            const float* A  = (o < 2 * d) ? A1 : A2;    // [8, d]
            const float* Bm = (o < 2 * d) ? B1 : B2;    // [d, 8]
            int r0 = o - ((o < 2 * d) ? d : 2 * d);
#pragma unroll
            for (int r = 0; r < 8; ++r) {
                float bb = Bm[(size_t)r0 * 8 + r];
                const float4* arow = (const float4*)(A + (size_t)r * d + k0);
                float4 a0 = arow[0], a1 = arow[1];
                acc[0] += bb * a0.x; acc[1] += bb * a0.y;
                acc[2] += bb * a0.z; acc[3] += bb * a0.w;
                acc[4] += bb * a1.x; acc[5] += bb * a1.y;
                acc[6] += bb * a1.z; acc[7] += bb * a1.w;
            }
        }
        ushort8 ov;
#pragma unroll
        for (int c = 0; c < 8; ++c) ov[c] = f2bf(acc[c]);
        ((ushort8*)(Wb + (size_t)o * d))[threadIdx.x] = ov;
    } else {
        int i = (blk - nW) * 256 + threadIdx.x;
        if (i >= n8) return;
        const float4* s = (const float4*)x + (size_t)i * 2;
        float4 a = s[0], c = s[1];
        ushort8 o;
        o[0] = f2bf(a.x); o[1] = f2bf(a.y); o[2] = f2bf(a.z); o[3] = f2bf(a.w);
        o[4] = f2bf(c.x); o[5] = f2bf(c.y); o[6] = f2bf(c.z); o[7] = f2bf(c.w);
        ((ushort8*)Xb)[i] = o;
    }
}

// ---------- kernel 2: 256x256 tile, BK=64, 8-phase counted-vmcnt + phase-hoisted ds_reads ----
// 512 thr = 8 waves (2M x 4N); per-wave 128x64 output = acc[4][2] of 32x32x16 MFMA.
// LDS: 2 buffers x (A 32KB + B 32KB) = 128 KiB. Chunk-XOR swizzle unchanged.
//
// CHANGE vs prev round: each MFMA cluster's ds_reads are issued ONE PHASE EARLY, so the
// compiler's auto lgkmcnt before the cluster is a counted wait on already-complete loads
// and the LDS burst overlaps the previous cluster's MFMA execution (was: serial
// read->lgkm(0)->MFMA per phase, measured 39% MfmaUtil = pipes running back-to-back).
// Cluster order per tile v (buf q): C1=acc[0..1][0] (aq0 x b0), C2=acc[0..1][1] (aq0 x b1),
// C3=acc[2..3][0] (aq1 x b0), C4=acc[2..3][1] (aq1 x b1).
// Read issues: ph1 -> b1(4);  ph2 -> aq1(8);  ph3 -> none;  ph4 (after vmcnt(4)+BAR) ->
// aq0',b0' of tile v+1 (12). Register liveness makes this free: aq0 dead after C2,
// b0 dead after C3, b1/aq1 reloaded next tile after C4.
// vmcnt(4) stays at ph4 and covers ALL tile-v+1 reads (they all occur after it); the
// youngest load it retires was staged 2 phases earlier (>> 900cy HBM latency) -> no stall.
// LDS WAR audit: every STAGE to a region is >=2 barriers after the region's last reader's
// pre-MFMA lgkm wait; every hoisted read targets regions whose stages were retired by the
// previous tile's vmcnt(4).
constexpr int BM = 256, BN = 256, BK = 64;
constexpr int KK = 2048, NN = 6144;       // fixed by problem shape
constexpr int TT = KK / BK;               // 32 K-tiles

__global__ __launch_bounds__(512, 2) void gemm256_kernel(
    const unsigned short* __restrict__ Xb,
    const unsigned short* __restrict__ Wb,
    const float* __restrict__ bias,
    float* __restrict__ out,
    int M)
{
    __shared__ __align__(16) unsigned short As[2][BM * BK];   // 2 x 32 KiB
    __shared__ __align__(16) unsigned short Bs[2][BN * BK];   // 2 x 32 KiB

    const int tid  = threadIdx.x;
    const int wave = tid >> 6;
    const int lane = tid & 63;
    const int half = lane >> 5;
    const int ln32 = lane & 31;
    const int wrow = wave >> 2;       // 0..1  -> row offset *128
    const int wcol = wave & 3;        // 0..3  -> col offset *64

    // ---- XCD-aware block swizzle (bijective: 768 % 8 == 0) ----
    int nwg = (int)gridDim.x;
    int bid = (int)blockIdx.x;
    int swz = bid;
    if ((nwg & 7) == 0) swz = (bid & 7) * (nwg >> 3) + (bid >> 3);
    const int ntn = NN / BN;          // 24
    const int bm = (swz / ntn) * BM;
    const int bn = (swz % ntn) * BN;

    // ---- staging per-thread constants: call = 64 rows x 8 chunks = 512 lanes ----
    const int rtid = tid >> 3;                     // row-in-call 0..63
    const int ctid = (tid & 7) ^ (rtid & 7);       // swizzled global chunk
    const size_t gA0 = (size_t)(bm + rtid) * KK + ctid * 8;
    const size_t gB0 = (size_t)(bn + rtid) * KK + ctid * 8;
    const int ldsW = wave * 512;                   // shorts: wave covers 8 rows/call

#define STAGE_A(t, j, buf) gload_lds16(Xb + gA0 + (size_t)(j) * 64 * KK + (size_t)(t) * BK, \
                                       &As[(buf)][(j) * 4096 + ldsW])
#define STAGE_B(t, j, buf) gload_lds16(Wb + gB0 + (size_t)(j) * 64 * KK + (size_t)(t) * BK, \
                                       &Bs[(buf)][(j) * 4096 + ldsW])

    // ---- fragment read offsets ----
    const int r7 = ln32 & 7;
    int dofs[4];
#pragma unroll
    for (int s = 0; s < 4; ++s) dofs[s] = ((s * 2 + half) ^ r7) * 8;
    int baseA[2][2];                  // [qm][f]
#pragma unroll
    for (int qm = 0; qm < 2; ++qm)
#pragma unroll
        for (int f = 0; f < 2; ++f)
            baseA[qm][f] = (wrow * 128 + qm * 64 + f * 32 + ln32) * BK;
    int baseB[2];                     // [qn]
#pragma unroll
    for (int qn = 0; qn < 2; ++qn) baseB[qn] = (wcol * 64 + qn * 32 + ln32) * BK;

    f32x16 acc[4][2];
#pragma unroll
    for (int i = 0; i < 4; ++i)
#pragma unroll
        for (int j = 0; j < 2; ++j)
#pragma unroll
            for (int r = 0; r < 16; ++r) acc[i][j][r] = 0.f;

    // A fragment sets for qm0 / qm1 held simultaneously (pipelined reload)
    bf16x8 a0f[2][4], a1f[2][4], b0[4], b1[4];

#define LOAD_AQ(SRC, qm, DST) do { _Pragma("unroll") for (int s = 0; s < 4; ++s) {  \
        DST[0][s] = *(const bf16x8*)&(SRC)[baseA[qm][0] + dofs[s]];                 \
        DST[1][s] = *(const bf16x8*)&(SRC)[baseA[qm][1] + dofs[s]]; } } while (0)
#define LOAD_BQ(SRC, qn, DST) do { _Pragma("unroll") for (int s = 0; s < 4; ++s) {  \
        DST[s] = *(const bf16x8*)&(SRC)[baseB[qn] + dofs[s]]; } } while (0)
#define MFMA_CL(AF, i0, i1, jj, BB) do {                                            \
        __builtin_amdgcn_s_setprio(1);                                             \
        _Pragma("unroll") for (int s = 0; s < 4; ++s) {                            \
            acc[i0][jj] = __builtin_amdgcn_mfma_f32_32x32x16_bf16(AF[0][s], BB[s], acc[i0][jj], 0, 0, 0); \
            acc[i1][jj] = __builtin_amdgcn_mfma_f32_32x32x16_bf16(AF[1][s], BB[s], acc[i1][jj], 0, 0, 0); \
        }                                                                          \
        __builtin_amdgcn_s_setprio(0); } while (0)
#define BAR() asm volatile("s_barrier" ::: "memory")

// QQ = (v)&1 as a compile-time-foldable parameter; RN = issue next-tile reads at ph4.
#define GROUP(v, QQ, SN1, SN2, VMW, RN) do {                                       \
        const unsigned short* Aq  = &As[(QQ)][0];                                  \
        const unsigned short* Bq  = &Bs[(QQ)][0];                                  \
        const unsigned short* Aq2 = &As[(QQ) ^ 1][0];                              \
        const unsigned short* Bq2 = &Bs[(QQ) ^ 1][0];                              \
        /* ph1: issue reads for C2 (b1); MFMA C1 on data read last ph4 */          \
        LOAD_BQ(Bq, 1, b1);                                                        \
        if (SN1) { STAGE_B((v) + 1, 2, (QQ) ^ 1); STAGE_B((v) + 1, 3, (QQ) ^ 1); } \
        BAR();                                                                     \
        MFMA_CL(a0f, 0, 1, 0, b0);                                                 \
        BAR();                                                                     \
        /* ph2: issue reads for C3 (aq1); MFMA C2 */                               \
        LOAD_AQ(Aq, 1, a1f);                                                       \
        if (SN1) { STAGE_A((v) + 1, 1, (QQ) ^ 1); STAGE_A((v) + 1, 3, (QQ) ^ 1); } \
        BAR();                                                                     \
        MFMA_CL(a0f, 0, 1, 1, b1);                                                 \
        BAR();                                                                     \
        /* ph3: no reads; MFMA C3 */                                               \
        if (SN2) { STAGE_A((v) + 2, 0, (QQ)); STAGE_A((v) + 2, 2, (QQ)); }         \
        BAR();                                                                     \
        MFMA_CL(a1f, 2, 3, 0, b0);                                                 \
        BAR();                                                                     \
        /* ph4: vmcnt gate, then issue next-tile C1 reads under C4's MFMA */       \
        if (SN2) { STAGE_B((v) + 2, 0, (QQ)); STAGE_B((v) + 2, 1, (QQ)); }         \
        if ((VMW) == 4)      asm volatile("s_waitcnt vmcnt(4)" ::: "memory");      \
        else if ((VMW) == 0) asm volatile("s_waitcnt vmcnt(0)" ::: "memory");      \
        BAR();                                                                     \
        if (RN) { LOAD_AQ(Aq2, 0, a0f); LOAD_BQ(Bq2, 0, b0); }                     \
        MFMA_CL(a1f, 2, 3, 1, b1);                                                 \
        BAR();                                                                     \
    } while (0)

    // ---- prologue: tile0 fully + tile1 {A0,A2,B0,B1}; wait tile0 (4 left in flight);
    //      then pre-issue tile0's C1 reads (aq0,b0) ----
#pragma unroll
    for (int j = 0; j < 4; ++j) STAGE_A(0, j, 0);
#pragma unroll
    for (int j = 0; j < 4; ++j) STAGE_B(0, j, 0);
    STAGE_A(1, 0, 1); STAGE_A(1, 2, 1);
    STAGE_B(1, 0, 1); STAGE_B(1, 1, 1);
    asm volatile("s_waitcnt vmcnt(4)" ::: "memory");
    BAR();
    LOAD_AQ((&As[0][0]), 0, a0f);
    LOAD_BQ((&Bs[0][0]), 0, b0);

    // ---- main loop: steady groups (pairs keep QQ compile-time), then 2 tail groups ----
    for (int vv = 0; vv < TT - 2; vv += 2) {       // TT-2 = 30, even
        GROUP(vv,     0, 1, 1, 4, 1);
        GROUP(vv + 1, 1, 1, 1, 4, 1);
    }
    GROUP(TT - 2, 0, 1, 0, 0, 1);                  // drains vmcnt, reads tile TT-1
    GROUP(TT - 1, 1, 0, 0, -1, 0);                 // last tile, no next reads

#undef GROUP
#undef BAR
#undef MFMA_CL
#undef LOAD_BQ
#undef LOAD_AQ
#undef STAGE_B
#undef STAGE_A

    // ---- epilogue: C/D layout col=lane&31, row=(reg&3)+8*(reg>>2)+4*half (m74/m101) ----
#pragma unroll
    for (int j = 0; j < 2; ++j) {
        int col = bn + wcol * 64 + j * 32 + ln32;
        float bv = bias[col];
#pragma unroll
        for (int i = 0; i < 4; ++i) {
            int rbase = bm + wrow * 128 + i * 32 + 4 * half;
#pragma unroll
            for (int reg = 0; reg < 16; ++reg) {
                int row = rbase + (reg & 3) + 8 * (reg >> 2);
                out[(size_t)row * NN + col] = acc[i][j][reg] + bv;
            }
        }
    }
}

// ---------- launcher ----------
extern "C" void kernel_launch(void* const* d_in, const int* in_sizes, int n_in,
                              void* d_out, int out_size, void* d_ws, size_t ws_size,
                              hipStream_t stream) {
    const float* x  = (const float*)d_in[0];   // [4,2048,2048]
    const float* W  = (const float*)d_in[1];   // [6144,2048]
    const float* b  = (const float*)d_in[2];   // [6144]
    const float* A1 = (const float*)d_in[3];   // [8,2048]
    const float* B1 = (const float*)d_in[4];   // [2048,8]
    const float* A2 = (const float*)d_in[5];   // [8,2048]
    const float* B2 = (const float*)d_in[6];   // [2048,8]
    float* out = (float*)d_out;

    const int d = 2048;
    const int K = d;               // in_features
    const int N = 3 * d;           // 6144 fused rows
    const int M = in_sizes[0] / d; // 8192 = B*S

    unsigned short* Xbf = (unsigned short*)d_ws;              // M*K bf16 = 33.5 MB
    unsigned short* Wbf = Xbf + (size_t)M * K;                // N*K bf16 = 25.2 MB

    // 1) fused: Wb = bf16(W + delta); Xb = bf16(x)   [unchanged]
    int n8 = (M * K) / 8;
    int castBlocks = (n8 + 255) / 256;
    prep_kernel<<<N + castBlocks, 256, 0, stream>>>(x, W, A1, B1, A2, B2,
                                                    Xbf, Wbf, d, N, n8);

    // 2) GEMM + bias: 256x256 tiles, 8-phase schedule with hoisted ds_reads
    dim3 grid((M / BM) * (N / BN));   // 32*24 = 768
    gemm256_kernel<<<grid, 512, 0, stream>>>(Xbf, Wbf, b, out, M);
}

// Round 5
// 469.961 us; speedup vs baseline: 1.1303x; 1.1303x over previous
//
#include <hip/hip_runtime.h>
#include <hip/hip_bf16.h>
#include <stdint.h>
#include <stddef.h>

// ---------- types ----------
typedef __attribute__((ext_vector_type(8)))  __bf16 bf16x8;   // MFMA A/B frag (4 VGPRs)
typedef __attribute__((ext_vector_type(4)))  float  f32x4;    // 16x16 MFMA C/D frag
typedef __attribute__((ext_vector_type(8)))  unsigned short ushort8;

typedef const void __attribute__((address_space(1)))* as1_cvp;
typedef void       __attribute__((address_space(3)))* as3_vp;

__device__ __forceinline__ void gload_lds16(const void* g, void* l) {
    // width=16 -> global_load_lds_dwordx4. LDS dest = wave-uniform base + lane*16.
    __builtin_amdgcn_global_load_lds((as1_cvp)g, (as3_vp)l, 16, 0, 0);
}

__device__ __forceinline__ unsigned short f2bf(float f) {
    union { float f; unsigned u; } v; v.f = f;
    unsigned r = v.u + 0x7fffu + ((v.u >> 16) & 1u);   // RNE
    return (unsigned short)(r >> 16);
}

// ---------- kernel 1 (fused prep): blocks [0,nW) -> Wb row; blocks [nW,..) -> x cast ----------
// UNCHANGED (isolating the GEMM change).
__global__ __launch_bounds__(256) void prep_kernel(
    const float* __restrict__ x,
    const float* __restrict__ W,
    const float* __restrict__ A1, const float* __restrict__ B1,
    const float* __restrict__ A2, const float* __restrict__ B2,
    unsigned short* __restrict__ Xb, unsigned short* __restrict__ Wb,
    int d, int nW, int n8)
{
    int blk = blockIdx.x;
    if (blk < nW) {
        int o  = blk;
        int k0 = threadIdx.x * 8;
        const float4* wrow = (const float4*)(W + (size_t)o * d + k0);
        float4 w0 = wrow[0], w1 = wrow[1];
        float acc[8] = {w0.x, w0.y, w0.z, w0.w, w1.x, w1.y, w1.z, w1.w};
        if (o >= d) {                               // block-uniform branch
            const float* A  = (o < 2 * d) ? A1 : A2;    // [8, d]
            const float* Bm = (o < 2 * d) ? B1 : B2;    // [d, 8]
            int r0 = o - ((o < 2 * d) ? d : 2 * d);
#pragma unroll
            for (int r = 0; r < 8; ++r) {
                float bb = Bm[(size_t)r0 * 8 + r];
                const float4* arow = (const float4*)(A + (size_t)r * d + k0);
                float4 a0 = arow[0], a1 = arow[1];
                acc[0] += bb * a0.x; acc[1] += bb * a0.y;
                acc[2] += bb * a0.z; acc[3] += bb * a0.w;
                acc[4] += bb * a1.x; acc[5] += bb * a1.y;
                acc[6] += bb * a1.z; acc[7] += bb * a1.w;
            }
        }
        ushort8 ov;
#pragma unroll
        for (int c = 0; c < 8; ++c) ov[c] = f2bf(acc[c]);
        ((ushort8*)(Wb + (size_t)o * d))[threadIdx.x] = ov;
    } else {
        int i = (blk - nW) * 256 + threadIdx.x;
        if (i >= n8) return;
        const float4* s = (const float4*)x + (size_t)i * 2;
        float4 a = s[0], c = s[1];
        ushort8 o;
        o[0] = f2bf(a.x); o[1] = f2bf(a.y); o[2] = f2bf(a.z); o[3] = f2bf(a.w);
        o[4] = f2bf(c.x); o[5] = f2bf(c.y); o[6] = f2bf(c.z); o[7] = f2bf(c.w);
        ((ushort8*)Xb)[i] = o;
    }
}

// ---------- kernel 2: 256x256, BK=64, m201-style quadrant schedule, 16x16x32 MFMA ----------
// 512 thr = 8 waves (2M x 4N); wave tile 128x64 = acc[8][4] of f32x4.
// Per K-tile: 4 phases = 4 C-quadrants of 16 MFMA each; reads 12/4/8/0 b128/wave:
//  ph1: read A(rt0-3)+B(ct0-1) | stage A(t+1) j0,1 -> buf^1 | BAR | MFMA Q(rh0,ch0) | BAR
//  ph2: read B(ct2-3)          | stage A(t+1) j2,3 -> buf^1 | BAR | MFMA Q(rh0,ch1) | BAR
//  ph3: read A(rt4-7)          | stage B(t+2) j0,1 -> buf   | BAR | MFMA Q(rh1,ch1) | BAR
//  ph4: (b0 held since ph1)    | stage B(t+2) j2,3 -> buf   | vmcnt(4) | BAR | MFMA Q(rh1,ch0) | BAR
// Liveness: b0 ph1->ph4, b1 ph2->ph3, A-set reloaded at ph3 -> 64 frag VGPR peak (= R2,
// which fit at the 256-reg/wave budget with 0 spill; R3's +64-reg hoist spilled -> reverted).
// WAR audit: A(t+1)->buf^1 A-rows: last read (t-1).ph1/ph3, >=1 barrier + lgkm before.
//            B(t+2)->buf B-rows: last read t.ph1/ph2 (lgkm'd before ph2 MFMA, 2 barriers ago).
// RAW: one vmcnt(4) per tile at ph4 retires everything except the 4 B(t+2) stages =>
//      tile t+1 fully landed before (t+1).ph1. Never drains to 0 in steady state.
// Staging pipeline: A(s) issued at (s-1).ph1-2; B(s) at (s-2).ph3-4; 2 gload_lds/phase.
constexpr int BM = 256, BN = 256, BK = 64;
constexpr int KK = 2048, NN = 6144;       // fixed by problem shape
constexpr int TT = KK / BK;               // 32 K-tiles

__global__ __launch_bounds__(512, 2) void gemm256_kernel(
    const unsigned short* __restrict__ Xb,
    const unsigned short* __restrict__ Wb,
    const float* __restrict__ bias,
    float* __restrict__ out,
    int M)
{
    __shared__ __align__(16) unsigned short As[2][BM * BK];   // 2 x 32 KiB
    __shared__ __align__(16) unsigned short Bs[2][BN * BK];   // 2 x 32 KiB

    const int tid  = threadIdx.x;
    const int wave = tid >> 6;
    const int lane = tid & 63;
    const int l15  = lane & 15;
    const int l4   = lane >> 4;       // 0..3 -> k-group
    const int wrow = wave >> 2;       // 0..1  -> row offset *128
    const int wcol = wave & 3;        // 0..3  -> col offset *64

    // ---- XCD-aware block swizzle (bijective: 768 % 8 == 0) ----
    int nwg = (int)gridDim.x;
    int bid = (int)blockIdx.x;
    int swz = bid;
    if ((nwg & 7) == 0) swz = (bid & 7) * (nwg >> 3) + (bid >> 3);
    const int ntn = NN / BN;          // 24
    const int bm = (swz / ntn) * BM;
    const int bn = (swz % ntn) * BN;

    // ---- staging per-thread constants: call = 64 rows x 8 chunks = 512 lanes ----
    // LDS slot p of row r holds global k-chunk p^(r&7); lane-linear dest (rule #21).
    const int rtid = tid >> 3;                     // row-in-call 0..63
    const int ctid = (tid & 7) ^ (rtid & 7);       // swizzled global chunk
    const size_t gA0 = (size_t)(bm + rtid) * KK + ctid * 8;
    const size_t gB0 = (size_t)(bn + rtid) * KK + ctid * 8;
    const int ldsW = wave * 512;                   // shorts: wave covers 8 rows/call

#define STAGE_A(t, j, buf) gload_lds16(Xb + gA0 + (size_t)(j) * 64 * KK + (size_t)(t) * BK, \
                                       &As[(buf)][(j) * 4096 + ldsW])
#define STAGE_B(t, j, buf) gload_lds16(Wb + gB0 + (size_t)(j) * 64 * KK + (size_t)(t) * BK, \
                                       &Bs[(buf)][(j) * 4096 + ldsW])

    // ---- fragment read offsets (shorts) ----
    // frag(row-tile rt, kstep ks): lane: row = base + rt*16 + l15, chunk c = ks*4 + l4,
    // slot = c ^ (row&7) = c ^ (lane&7).
    int slotk[2];
#pragma unroll
    for (int ks = 0; ks < 2; ++ks) slotk[ks] = ((ks * 4 + l4) ^ (lane & 7)) * 8;
    const int rowAb = (wrow * 128 + l15) * 64;
    const int rowBb = (wcol * 64 + l15) * 64;

    f32x4 acc[8][4];
#pragma unroll
    for (int i = 0; i < 8; ++i)
#pragma unroll
        for (int j = 0; j < 4; ++j)
#pragma unroll
            for (int r = 0; r < 4; ++r) acc[i][j][r] = 0.f;

    bf16x8 a[4][2], b0[2][2], b1[2][2];

#define LOAD_A4(SRC, rh) do { _Pragma("unroll") for (int rt = 0; rt < 4; ++rt)      \
        { _Pragma("unroll") for (int ks = 0; ks < 2; ++ks)                          \
            a[rt][ks] = *(const bf16x8*)&(SRC)[rowAb + ((rh) * 4 + rt) * 1024 + slotk[ks]]; } } while (0)
#define LOAD_B2(SRC, ch, DST) do { _Pragma("unroll") for (int c2 = 0; c2 < 2; ++c2) \
        { _Pragma("unroll") for (int ks = 0; ks < 2; ++ks)                          \
            DST[c2][ks] = *(const bf16x8*)&(SRC)[rowBb + ((ch) * 2 + c2) * 1024 + slotk[ks]]; } } while (0)
// 16 MFMA = quadrant (rh, ch): 8 independent acc, dependent pairs ks0->ks1.
#define MFMA_PH(rh, ch, BB) do {                                                    \
        __builtin_amdgcn_s_setprio(1);                                             \
        _Pragma("unroll") for (int ks = 0; ks < 2; ++ks)                           \
        _Pragma("unroll") for (int c2 = 0; c2 < 2; ++c2)                           \
        _Pragma("unroll") for (int rt = 0; rt < 4; ++rt)                           \
            acc[(rh) * 4 + rt][(ch) * 2 + c2] = __builtin_amdgcn_mfma_f32_16x16x32_bf16( \
                a[rt][ks], BB[c2][ks], acc[(rh) * 4 + rt][(ch) * 2 + c2], 0, 0, 0);     \
        __builtin_amdgcn_s_setprio(0); } while (0)
#define BAR() asm volatile("s_barrier" ::: "memory")

#define GROUP16(v, QQ, S1, S2, VMW) do {                                           \
        const unsigned short* Aq = &As[(QQ)][0];                                   \
        const unsigned short* Bq = &Bs[(QQ)][0];                                   \
        /* ph1 */                                                                  \
        LOAD_A4(Aq, 0); LOAD_B2(Bq, 0, b0);                                        \
        if (S1) { STAGE_A((v) + 1, 0, (QQ) ^ 1); STAGE_A((v) + 1, 1, (QQ) ^ 1); }  \
        BAR();                                                                     \
        MFMA_PH(0, 0, b0);                                                         \
        BAR();                                                                     \
        /* ph2 */                                                                  \
        LOAD_B2(Bq, 1, b1);                                                        \
        if (S1) { STAGE_A((v) + 1, 2, (QQ) ^ 1); STAGE_A((v) + 1, 3, (QQ) ^ 1); }  \
        BAR();                                                                     \
        MFMA_PH(0, 1, b1);                                                         \
        BAR();                                                                     \
        /* ph3 */                                                                  \
        LOAD_A4(Aq, 1);                                                            \
        if (S2) { STAGE_B((v) + 2, 0, (QQ)); STAGE_B((v) + 2, 1, (QQ)); }          \
        BAR();                                                                     \
        MFMA_PH(1, 1, b1);                                                         \
        BAR();                                                                     \
        /* ph4 */                                                                  \
        if (S2) { STAGE_B((v) + 2, 2, (QQ)); STAGE_B((v) + 2, 3, (QQ)); }          \
        if ((VMW) == 4)      asm volatile("s_waitcnt vmcnt(4)" ::: "memory");      \
        else if ((VMW) == 0) asm volatile("s_waitcnt vmcnt(0)" ::: "memory");      \
        BAR();                                                                     \
        MFMA_PH(1, 0, b0);                                                         \
        BAR();                                                                     \
    } while (0)

    // ---- prologue: B(0), A(0), B(1); retire first 8, keep B(1) in flight ----
#pragma unroll
    for (int j = 0; j < 4; ++j) STAGE_B(0, j, 0);
#pragma unroll
    for (int j = 0; j < 4; ++j) STAGE_A(0, j, 0);
#pragma unroll
    for (int j = 0; j < 4; ++j) STAGE_B(1, j, 1);
    asm volatile("s_waitcnt vmcnt(4)" ::: "memory");
    BAR();

    // ---- main loop: steady pairs (compile-time buffer parity), then 2 tail tiles ----
    for (int vv = 0; vv < TT - 2; vv += 2) {       // TT-2 = 30, even
        GROUP16(vv,     0, 1, 1, 4);
        GROUP16(vv + 1, 1, 1, 1, 4);
    }
    GROUP16(TT - 2, 0, 1, 0, 0);                   // stages A(TT-1), drains
    GROUP16(TT - 1, 1, 0, 0, -1);                  // last tile, no stages

#undef GROUP16
#undef BAR
#undef MFMA_PH
#undef LOAD_B2
#undef LOAD_A4
#undef STAGE_B
#undef STAGE_A

    // ---- epilogue: 16x16 C/D layout col=lane&15, row=(lane>>4)*4+reg (m89/m91) ----
#pragma unroll
    for (int ct = 0; ct < 4; ++ct) {
        int col = bn + wcol * 64 + ct * 16 + l15;
        float bv = bias[col];
#pragma unroll
        for (int rt = 0; rt < 8; ++rt) {
            int rbase = bm + wrow * 128 + rt * 16 + l4 * 4;
#pragma unroll
            for (int reg = 0; reg < 4; ++reg) {
                out[(size_t)(rbase + reg) * NN + col] = acc[rt][ct][reg] + bv;
            }
        }
    }
}

// ---------- launcher ----------
extern "C" void kernel_launch(void* const* d_in, const int* in_sizes, int n_in,
                              void* d_out, int out_size, void* d_ws, size_t ws_size,
                              hipStream_t stream) {
    const float* x  = (const float*)d_in[0];   // [4,2048,2048]
    const float* W  = (const float*)d_in[1];   // [6144,2048]
    const float* b  = (const float*)d_in[2];   // [6144]
    const float* A1 = (const float*)d_in[3];   // [8,2048]
    const float* B1 = (const float*)d_in[4];   // [2048,8]
    const float* A2 = (const float*)d_in[5];   // [8,2048]
    const float* B2 = (const float*)d_in[6];   // [2048,8]
    float* out = (float*)d_out;

    const int d = 2048;
    const int K = d;               // in_features
    const int N = 3 * d;           // 6144 fused rows
    const int M = in_sizes[0] / d; // 8192 = B*S

    unsigned short* Xbf = (unsigned short*)d_ws;              // M*K bf16 = 33.5 MB
    unsigned short* Wbf = Xbf + (size_t)M * K;                // N*K bf16 = 25.2 MB

    // 1) fused: Wb = bf16(W + delta); Xb = bf16(x)   [unchanged]
    int n8 = (M * K) / 8;
    int castBlocks = (n8 + 255) / 256;
    prep_kernel<<<N + castBlocks, 256, 0, stream>>>(x, W, A1, B1, A2, B2,
                                                    Xbf, Wbf, d, N, n8);

    // 2) GEMM + bias: 256x256 tiles, quadrant schedule, 16x16x32 MFMA
    dim3 grid((M / BM) * (N / BN));   // 32*24 = 768
    gemm256_kernel<<<grid, 512, 0, stream>>>(Xbf, Wbf, b, out, M);
}